// Round 1
// baseline (131.365 us; speedup 1.0000x reference)
//
#include <hip/hip_runtime.h>

// Mean-pool consecutive chunks of g=4 rows: out[j,:] = mean(x[4j:4j+4, :])
// x: [BATCH*SEQLEN, DIM] fp32 = [131072, 1024]; out: [32768, 1024] fp32.
// Pure streaming op: 512 MiB read + 128 MiB write, HBM-bound.
//
// Vectorized as float4 (16 B/lane). DIM = 1024 fp32 = 256 float4 per row.
// Output float4 index o: row j = o>>8, col c = o&255.
// Input float4 base for row 4j = j*1024 + c; rows at +0,+256,+512,+768.
// All 4 loads + store are lane-contiguous -> fully coalesced.

#define ROW_F4 256          // float4 per row (DIM=1024)
#define GROUP 4             // |comp_rate|

__global__ void pool_mean4_kernel(const float4* __restrict__ in,
                                  float4* __restrict__ out,
                                  long n_out4) {
    long stride = (long)gridDim.x * blockDim.x;
    for (long o = (long)blockIdx.x * blockDim.x + threadIdx.x; o < n_out4; o += stride) {
        long j = o >> 8;            // output row
        long c = o & (ROW_F4 - 1);  // float4 column
        long base = j * (ROW_F4 * GROUP) + c;
        float4 a = in[base];
        float4 b = in[base + ROW_F4];
        float4 d = in[base + 2 * ROW_F4];
        float4 e = in[base + 3 * ROW_F4];
        float4 r;
        r.x = (a.x + b.x + d.x + e.x) * 0.25f;
        r.y = (a.y + b.y + d.y + e.y) * 0.25f;
        r.z = (a.z + b.z + d.z + e.z) * 0.25f;
        r.w = (a.w + b.w + d.w + e.w) * 0.25f;
        out[o] = r;
    }
}

extern "C" void kernel_launch(void* const* d_in, const int* in_sizes, int n_in,
                              void* d_out, int out_size, void* d_ws, size_t ws_size,
                              hipStream_t stream) {
    const float4* x = (const float4*)d_in[0];
    float4* out = (float4*)d_out;

    // out_size = total_rows/4 * DIM fp32 elements; n_out4 in float4 units.
    long n_out4 = (long)out_size / 4;

    const int block = 256;
    // memory-bound: cap at 256 CU x 8 blocks and grid-stride the rest
    long want = (n_out4 + block - 1) / block;
    int grid = (int)(want < 2048 ? want : 2048);

    pool_mean4_kernel<<<grid, block, 0, stream>>>(x, out, n_out4);
}

// Round 3
// 117.997 us; speedup vs baseline: 1.1133x; 1.1133x over previous
//
#include <hip/hip_runtime.h>

// Mean-pool consecutive chunks of g=4 rows: out[j,:] = mean(x[4j:4j+4, :])
// x: [131072, 1024] fp32; out: [32768, 1024] fp32.
// Streaming: 512 MiB read + 128 MiB write, HBM-bound. Floor ~102 us @ 6.3 TB/s.
//
// R2: same as R1 but using clang native vector type (ext_vector_type) --
// __builtin_nontemporal_load/store rejects HIP_vector_type (float4 class).

#define ROW_F4 256          // float4 per row (DIM=1024)
#define GROUP 4             // |comp_rate|

typedef float f4 __attribute__((ext_vector_type(4)));

__device__ __forceinline__ f4 mean4_at(const f4* __restrict__ in, long o) {
    long j = o >> 8;            // output row
    long c = o & (ROW_F4 - 1);  // float4 column
    long base = j * (ROW_F4 * GROUP) + c;
    f4 a = __builtin_nontemporal_load(&in[base]);
    f4 b = __builtin_nontemporal_load(&in[base + ROW_F4]);
    f4 d = __builtin_nontemporal_load(&in[base + 2 * ROW_F4]);
    f4 e = __builtin_nontemporal_load(&in[base + 3 * ROW_F4]);
    return (a + b + d + e) * 0.25f;
}

__global__ void pool_mean4_kernel(const f4* __restrict__ in,
                                  f4* __restrict__ out,
                                  long n_out4) {
    long stride = (long)gridDim.x * blockDim.x;
    long o = (long)blockIdx.x * blockDim.x + threadIdx.x;
    // 2x unrolled main loop: 8 loads outstanding before first use.
    for (; o + stride < n_out4; o += 2 * stride) {
        f4 r0 = mean4_at(in, o);
        f4 r1 = mean4_at(in, o + stride);
        __builtin_nontemporal_store(r0, &out[o]);
        __builtin_nontemporal_store(r1, &out[o + stride]);
    }
    if (o < n_out4) {
        f4 r0 = mean4_at(in, o);
        __builtin_nontemporal_store(r0, &out[o]);
    }
}

extern "C" void kernel_launch(void* const* d_in, const int* in_sizes, int n_in,
                              void* d_out, int out_size, void* d_ws, size_t ws_size,
                              hipStream_t stream) {
    const f4* x = (const f4*)d_in[0];
    f4* out = (f4*)d_out;

    long n_out4 = (long)out_size / 4;   // out_size fp32 elems -> float4 units

    const int block = 256;
    long want = (n_out4 + block - 1) / block;
    int grid = (int)(want < 2048 ? want : 2048);

    pool_mean4_kernel<<<grid, block, 0, stream>>>(x, out, n_out4);
}

// Round 4
// 116.858 us; speedup vs baseline: 1.1241x; 1.0097x over previous
//
#include <hip/hip_runtime.h>

// Mean-pool consecutive chunks of g=4 rows: out[j,:] = mean(x[4j:4j+4, :])
// x: [131072, 1024] fp32; out: [32768, 1024] fp32.
// Streaming: 512 MiB read + 128 MiB write, HBM-bound. Floor ~102 us @ 6.3 TB/s.
//
// R3: 4x unroll -> 16 independent nontemporal float4 loads in flight per
// loop trip; n_out4 = 8Mi, stride = 512Ki -> exactly 4 clean trips, no tail
// (guarded anyway for safety).

#define ROW_F4 256          // float4 per row (DIM=1024)
#define GROUP 4             // |comp_rate|

typedef float f4 __attribute__((ext_vector_type(4)));

__device__ __forceinline__ f4 mean4_at(const f4* __restrict__ in, long o) {
    long j = o >> 8;            // output row
    long c = o & (ROW_F4 - 1);  // float4 column
    long base = j * (ROW_F4 * GROUP) + c;
    f4 a = __builtin_nontemporal_load(&in[base]);
    f4 b = __builtin_nontemporal_load(&in[base + ROW_F4]);
    f4 d = __builtin_nontemporal_load(&in[base + 2 * ROW_F4]);
    f4 e = __builtin_nontemporal_load(&in[base + 3 * ROW_F4]);
    return (a + b + d + e) * 0.25f;
}

__global__ void pool_mean4_kernel(const f4* __restrict__ in,
                                  f4* __restrict__ out,
                                  long n_out4) {
    long stride = (long)gridDim.x * blockDim.x;
    long o = (long)blockIdx.x * blockDim.x + threadIdx.x;
    // 4x unrolled main loop: 16 loads outstanding before first use.
    for (; o + 3 * stride < n_out4; o += 4 * stride) {
        f4 r0 = mean4_at(in, o);
        f4 r1 = mean4_at(in, o + stride);
        f4 r2 = mean4_at(in, o + 2 * stride);
        f4 r3 = mean4_at(in, o + 3 * stride);
        __builtin_nontemporal_store(r0, &out[o]);
        __builtin_nontemporal_store(r1, &out[o + stride]);
        __builtin_nontemporal_store(r2, &out[o + 2 * stride]);
        __builtin_nontemporal_store(r3, &out[o + 3 * stride]);
    }
    for (; o < n_out4; o += stride) {
        f4 r0 = mean4_at(in, o);
        __builtin_nontemporal_store(r0, &out[o]);
    }
}

extern "C" void kernel_launch(void* const* d_in, const int* in_sizes, int n_in,
                              void* d_out, int out_size, void* d_ws, size_t ws_size,
                              hipStream_t stream) {
    const f4* x = (const f4*)d_in[0];
    f4* out = (f4*)d_out;

    long n_out4 = (long)out_size / 4;   // out_size fp32 elems -> float4 units

    const int block = 256;
    long want = (n_out4 + block - 1) / block;
    int grid = (int)(want < 2048 ? want : 2048);

    pool_mean4_kernel<<<grid, block, 0, stream>>>(x, out, n_out4);
}

// Round 5
// 115.383 us; speedup vs baseline: 1.1385x; 1.0128x over previous
//
#include <hip/hip_runtime.h>

// Mean-pool consecutive chunks of g=4 rows: out[j,:] = mean(x[4j:4j+4, :])
// x: [131072, 1024] fp32; out: [32768, 1024] fp32.
// Streaming: 512 MiB read + 128 MiB write, HBM-bound.
//
// R4 experiment: nt LOADS (512 MiB read stream must not pollute L2/L3) but
// REGULAR stores -- the 128 MiB output fits in the 256 MiB Infinity Cache,
// so plain stores can retire at L3 speed and drain lazily, instead of nt
// stores pushing eagerly to HBM inside the kernel window.

#define ROW_F4 256          // float4 per row (DIM=1024)
#define GROUP 4             // |comp_rate|

typedef float f4 __attribute__((ext_vector_type(4)));

__device__ __forceinline__ f4 mean4_at(const f4* __restrict__ in, long o) {
    long j = o >> 8;            // output row
    long c = o & (ROW_F4 - 1);  // float4 column
    long base = j * (ROW_F4 * GROUP) + c;
    f4 a = __builtin_nontemporal_load(&in[base]);
    f4 b = __builtin_nontemporal_load(&in[base + ROW_F4]);
    f4 d = __builtin_nontemporal_load(&in[base + 2 * ROW_F4]);
    f4 e = __builtin_nontemporal_load(&in[base + 3 * ROW_F4]);
    return (a + b + d + e) * 0.25f;
}

__global__ void pool_mean4_kernel(const f4* __restrict__ in,
                                  f4* __restrict__ out,
                                  long n_out4) {
    long stride = (long)gridDim.x * blockDim.x;
    long o = (long)blockIdx.x * blockDim.x + threadIdx.x;
    // 4x unrolled main loop: 16 nt loads outstanding before first use.
    for (; o + 3 * stride < n_out4; o += 4 * stride) {
        f4 r0 = mean4_at(in, o);
        f4 r1 = mean4_at(in, o + stride);
        f4 r2 = mean4_at(in, o + 2 * stride);
        f4 r3 = mean4_at(in, o + 3 * stride);
        out[o]              = r0;   // regular stores: land in L2/L3,
        out[o + stride]     = r1;   // drain to HBM lazily (output fits L3)
        out[o + 2 * stride] = r2;
        out[o + 3 * stride] = r3;
    }
    for (; o < n_out4; o += stride) {
        out[o] = mean4_at(in, o);
    }
}

extern "C" void kernel_launch(void* const* d_in, const int* in_sizes, int n_in,
                              void* d_out, int out_size, void* d_ws, size_t ws_size,
                              hipStream_t stream) {
    const f4* x = (const f4*)d_in[0];
    f4* out = (f4*)d_out;

    long n_out4 = (long)out_size / 4;   // out_size fp32 elems -> float4 units

    const int block = 256;
    long want = (n_out4 + block - 1) / block;
    int grid = (int)(want < 2048 ? want : 2048);

    pool_mean4_kernel<<<grid, block, 0, stream>>>(x, out, n_out4);
}